// Round 2
// baseline (975.025 us; speedup 1.0000x reference)
//
#include <hip/hip_runtime.h>
#include <hip/hip_bf16.h>

// CombineEmbedder: N=262144 rows, FEAT=64, D=128, DEPTH=2, N_LAYERS=1.
// All float tensors are fp32 on device (reference is jnp.float32 throughout;
// the "(bf16, ...)" in the harness error label is static template text).
// Row N (appended zero row) is never gathered (ids in [0,N)) and is dropped
// from all outputs -> skip it entirely.
//
// Buffers:
//   x0 (fp32)  = d_out's x_main region  [N][128]
//   x1 (bf16)  = d_ws (64 MB)           [N][128]  -- bf16 round-trip adds
//                <= ~0.016 abs error at |x|<=4, far under the 0.073 threshold.
// Schedule:
//   phase_a : feats -> x0
//   prop #1 : x0 (fp32) -> x1 (bf16)
//   prop #2 : x1 (bf16) -> x0 (fp32) + w, v heads

#define NROWS 262144
#define FEAT 64
#define DD 128
#define ROWS 4   // rows per block: amortize weight loads 4x

__device__ __forceinline__ float ld(const float* p, size_t i) { return p[i]; }
__device__ __forceinline__ float ld(const __hip_bfloat16* p, size_t i) { return __bfloat162float(p[i]); }
__device__ __forceinline__ void st(float* p, size_t i, float v) { p[i] = v; }
__device__ __forceinline__ void st(__hip_bfloat16* p, size_t i, float v) { p[i] = __float2bfloat16(v); }
__device__ __forceinline__ float leaky(float x) { return x >= 0.0f ? x : 0.01f * x; }

__global__ void __launch_bounds__(DD)
phase_a_kernel(const float* __restrict__ feats,
               const float* __restrict__ smean,
               const float* __restrict__ sstd,
               const float* __restrict__ Wemb,   // [64][128]
               const float* __restrict__ bemb,   // [128]
               const float* __restrict__ Wl,     // [128][128]
               const float* __restrict__ bl,     // [128]
               float* __restrict__ xout)         // [N][128]
{
    const int r0 = blockIdx.x * ROWS;
    const int j  = threadIdx.x;              // 0..127 (output column)

    __shared__ float xin[ROWS][FEAT];
    __shared__ float hbuf[ROWS][DD];
    __shared__ float rs[ROWS][DD];
    __shared__ float rs2[ROWS][DD];

    // load + input normalization: ROWS*FEAT = 256 elems, 128 threads
    for (int idx = j; idx < ROWS * FEAT; idx += DD) {
        int r = idx >> 6, k = idx & 63;
        float f = feats[(size_t)(r0 + r) * FEAT + k];
        xin[r][k] = (f - smean[k]) / (sstd[k] + 0.001f);
    }
    __syncthreads();

    // h = leaky(x @ Wemb + bemb)
    float acc[ROWS];
    {
        float be = bemb[j];
        #pragma unroll
        for (int r = 0; r < ROWS; r++) acc[r] = be;
    }
    for (int k = 0; k < FEAT; k++) {
        float wk = Wemb[k * DD + j];         // coalesced across j
        #pragma unroll
        for (int r = 0; r < ROWS; r++) acc[r] += xin[r][k] * wk;
    }
    float hv[ROWS];
    #pragma unroll
    for (int r = 0; r < ROWS; r++) { hv[r] = leaky(acc[r]); hbuf[r][j] = hv[r]; }
    __syncthreads();

    // t = leaky(leaky(h @ Wl + bl)) + h
    float acc2[ROWS];
    {
        float bb = bl[j];
        #pragma unroll
        for (int r = 0; r < ROWS; r++) acc2[r] = bb;
    }
    for (int k = 0; k < DD; k++) {
        float wk = Wl[k * DD + j];
        #pragma unroll
        for (int r = 0; r < ROWS; r++) acc2[r] += hbuf[r][k] * wk;
    }
    float tv[ROWS];
    #pragma unroll
    for (int r = 0; r < ROWS; r++) tv[r] = leaky(leaky(acc2[r])) + hv[r];

    // layernorm over D=128, then * 0.5
    #pragma unroll
    for (int r = 0; r < ROWS; r++) { rs[r][j] = tv[r]; rs2[r][j] = tv[r] * tv[r]; }
    __syncthreads();
    for (int s = 64; s > 0; s >>= 1) {
        if (j < s) {
            #pragma unroll
            for (int r = 0; r < ROWS; r++) { rs[r][j] += rs[r][j + s]; rs2[r][j] += rs2[r][j + s]; }
        }
        __syncthreads();
    }
    #pragma unroll
    for (int r = 0; r < ROWS; r++) {
        float mu  = rs[r][0] * (1.0f / DD);
        float var = rs2[r][0] * (1.0f / DD) - mu * mu;
        float xv  = (tv[r] - mu) * rsqrtf(var + 1e-5f) * 0.5f;
        xout[(size_t)(r0 + r) * DD + j] = xv;
    }
}

template <typename TIN, typename TOUT>
__global__ void __launch_bounds__(DD)
prop_kernel(const TIN* __restrict__ xin,          // [N][128]
            const int* __restrict__ idmap,        // [N][2]
            const float* __restrict__ Wn,         // [128][128]
            const float* __restrict__ bn,         // [128]
            const float* __restrict__ rez,        // [1]
            const float* __restrict__ Ww,         // [128]
            const float* __restrict__ Wv,         // [128]
            TOUT* __restrict__ xout,              // [N][128]
            float* __restrict__ wout,             // [N]  (final only)
            float* __restrict__ vout,             // [N]  (final only)
            int final_pass)
{
    const int r0 = blockIdx.x * ROWS;
    const int j  = threadIdx.x;

    __shared__ float fbuf[ROWS][DD];
    __shared__ float rs[ROWS][DD];
    __shared__ float rs2[ROWS][DD];

    // gather-mean of two neighbor rows (coalesced 512B row reads)
    #pragma unroll
    for (int r = 0; r < ROWS; r++) {
        int i0 = idmap[2 * (r0 + r)];
        int i1 = idmap[2 * (r0 + r) + 1];
        fbuf[r][j] = 0.5f * (ld(xin, (size_t)i0 * DD + j) + ld(xin, (size_t)i1 * DD + j));
    }
    __syncthreads();

    // g = leaky(f @ Wn + bn)
    float acc[ROWS];
    {
        float bb = bn[j];
        #pragma unroll
        for (int r = 0; r < ROWS; r++) acc[r] = bb;
    }
    for (int k = 0; k < DD; k++) {
        float wk = Wn[k * DD + j];
        #pragma unroll
        for (int r = 0; r < ROWS; r++) acc[r] += fbuf[r][k] * wk;
    }

    const float scale = 0.25f * rez[0];    // SCALE_STEPS * rezero
    float xn[ROWS];
    #pragma unroll
    for (int r = 0; r < ROWS; r++) {
        float g = leaky(acc[r]);
        xn[r] = ld(xin, (size_t)(r0 + r) * DD + j) + g * scale;
        st(xout, (size_t)(r0 + r) * DD + j, xn[r]);
    }

    if (final_pass) {
        float wwj = Ww[j], wvj = Wv[j];
        #pragma unroll
        for (int r = 0; r < ROWS; r++) { rs[r][j] = xn[r] * wwj; rs2[r][j] = xn[r] * wvj; }
        __syncthreads();
        for (int s = 64; s > 0; s >>= 1) {
            if (j < s) {
                #pragma unroll
                for (int r = 0; r < ROWS; r++) { rs[r][j] += rs[r][j + s]; rs2[r][j] += rs2[r][j + s]; }
            }
            __syncthreads();
        }
        if (j == 0) {
            #pragma unroll
            for (int r = 0; r < ROWS; r++) {
                wout[r0 + r] = rs[r][0];
                vout[r0 + r] = rs2[r][0];
            }
        }
    }
}

extern "C" void kernel_launch(void* const* d_in, const int* in_sizes, int n_in,
                              void* d_out, int out_size, void* d_ws, size_t ws_size,
                              hipStream_t stream) {
    const float* feats = (const float*)d_in[0];
    // d_in[1] = uids (unused by reference)
    const int*   idmap = (const int*)d_in[2];
    const float* smean = (const float*)d_in[3];
    const float* sstd  = (const float*)d_in[4];
    const float* Wemb  = (const float*)d_in[5];
    const float* bemb  = (const float*)d_in[6];
    const float* Wl    = (const float*)d_in[7];   // (1,128,128)
    const float* bl    = (const float*)d_in[8];   // (1,128)
    const float* Wn    = (const float*)d_in[9];
    const float* bn    = (const float*)d_in[10];
    const float* rez   = (const float*)d_in[11];
    const float* Ww    = (const float*)d_in[12];
    const float* Wv    = (const float*)d_in[13];

    float* out  = (float*)d_out;
    float* x0   = out;                                   // x_main region doubles as buffer 0
    __hip_bfloat16* x1 = (__hip_bfloat16*)d_ws;          // 64 MB ping-pong buffer (bf16)
    float* wout = out + (size_t)NROWS * DD;
    float* vout = wout + NROWS;

    dim3 grid(NROWS / ROWS), block(DD);
    phase_a_kernel<<<grid, block, 0, stream>>>(feats, smean, sstd, Wemb, bemb, Wl, bl, x0);
    prop_kernel<float, __hip_bfloat16><<<grid, block, 0, stream>>>(
        x0, idmap, Wn, bn, rez, Ww, Wv, x1, nullptr, nullptr, 0);
    prop_kernel<__hip_bfloat16, float><<<grid, block, 0, stream>>>(
        x1, idmap, Wn, bn, rez, Ww, Wv, x0, wout, vout, 1);
}

// Round 3
// 410.464 us; speedup vs baseline: 2.3754x; 2.3754x over previous
//
#include <hip/hip_runtime.h>

// CombineEmbedder MFMA rewrite. N=262144, FEAT=64, D=128, DEPTH=2.
// All device tensors fp32 (reference dtype); internal pipeline bf16:
//   phase_a : feats(fp32) -> x0 bf16   (x0 = first 64MB of d_out, dead later)
//   prop#1  : x0 bf16     -> x1 bf16   (x1 = d_ws, 64MB)
//   prop#2  : x1 bf16     -> x_main fp32 (d_out) + w,v heads
// MFMA 16x16x32 bf16; A layout A[m=lane&15][k=(lane>>4)*8+j];
// B via W^T staged in LDS (row stride 72/136 shorts -> 2-way bank alias, free);
// C/D: col=lane&15, row=(lane>>4)*4+reg.

#define NROWS 262144
#define NBLK  4096   // NROWS/64

typedef __attribute__((ext_vector_type(8))) short bhalf8;
typedef __attribute__((ext_vector_type(4))) float f32x4;
typedef __attribute__((ext_vector_type(4))) unsigned int u32x4;

__device__ __forceinline__ unsigned short f2bf(float x) {
    union { float f; unsigned u; } v; v.f = x;
    unsigned r = v.u + 0x7FFFu + ((v.u >> 16) & 1u);   // RNE
    return (unsigned short)(r >> 16);
}
__device__ __forceinline__ float bf2f(unsigned short b) {
    union { unsigned u; float f; } v; v.u = ((unsigned)b) << 16;
    return v.f;
}
__device__ __forceinline__ float leaky(float x) { return x >= 0.0f ? x : 0.01f * x; }

// ---------------- phase A: embed + residual layer + layernorm*0.5 ----------------
__global__ void __launch_bounds__(256)
phase_a_kernel(const float* __restrict__ feats, const float* __restrict__ smean,
               const float* __restrict__ sstd, const float* __restrict__ Wemb,
               const float* __restrict__ bemb, const float* __restrict__ Wl,
               const float* __restrict__ bl, unsigned short* __restrict__ xout)
{
    __shared__ __align__(16) short smem[26112];          // 52224 B -> 3 blocks/CU
    short* xin   = smem;            // [64][72]   bf16 normalized input
    short* wembT = smem + 4608;     // [128][72]  Wemb^T  (n-major, k inner)
    short* wlT   = smem;            // [128][136] Wl^T    (aliases xin+wembT)
    short* hb    = smem + 17408;    // [64][136]  h / final staging

    const int tid  = threadIdx.x;
    const int lane = tid & 63;
    const int wv   = tid >> 6;       // wave 0..3, owns rows wv*16..+15
    const int m    = lane & 15;
    const int q    = lane >> 4;
    const int r0   = blockIdx.x * 64;

    // stage normalized input (bf16), coalesced
    for (int idx = tid; idx < 64 * 64; idx += 256) {
        int r = idx >> 6, k = idx & 63;
        float f = feats[(size_t)(r0 + r) * 64 + k];
        xin[r * 72 + k] = (short)f2bf((f - smean[k]) / (sstd[k] + 0.001f));
    }
    // stage Wemb^T: coalesced global reads (per j), b128 LDS writes
    for (int c = tid; c < 128 * 8; c += 256) {
        int n = c & 127, kb = c >> 7;
        bhalf8 t;
        #pragma unroll
        for (int j = 0; j < 8; j++) t[j] = (short)f2bf(Wemb[(kb * 8 + j) * 128 + n]);
        *reinterpret_cast<bhalf8*>(&wembT[n * 72 + kb * 8]) = t;
    }
    __syncthreads();

    // matmul1: acc = x @ Wemb  (K=64, 2 ksteps x 8 ntiles)
    f32x4 acc[8] = {};
    #pragma unroll
    for (int s = 0; s < 2; s++) {
        bhalf8 a = *reinterpret_cast<const bhalf8*>(&xin[(wv * 16 + m) * 72 + s * 32 + q * 8]);
        #pragma unroll
        for (int t = 0; t < 8; t++) {
            bhalf8 b = *reinterpret_cast<const bhalf8*>(&wembT[(t * 16 + m) * 72 + s * 32 + q * 8]);
            acc[t] = __builtin_amdgcn_mfma_f32_16x16x32_bf16(a, b, acc[t], 0, 0, 0);
        }
    }
    __syncthreads();   // all waves done reading xin/wembT; wlT restages over them

    // h = leaky(acc + bemb) -> hb (bf16, C-layout positions, own rows only)
    #pragma unroll
    for (int t = 0; t < 8; t++) {
        float be = bemb[t * 16 + m];
        #pragma unroll
        for (int p = 0; p < 4; p++) {
            int row = wv * 16 + q * 4 + p;
            hb[row * 136 + t * 16 + m] = (short)f2bf(leaky(acc[t][p] + be));
        }
    }
    // stage Wl^T
    for (int c = tid; c < 128 * 16; c += 256) {
        int n = c & 127, kb = c >> 7;
        bhalf8 t;
        #pragma unroll
        for (int j = 0; j < 8; j++) t[j] = (short)f2bf(Wl[(kb * 8 + j) * 128 + n]);
        *reinterpret_cast<bhalf8*>(&wlT[n * 136 + kb * 8]) = t;
    }
    __syncthreads();

    // matmul2: acc2 = h @ Wl  (K=128, 4 ksteps x 8 ntiles)
    f32x4 acc2[8] = {};
    #pragma unroll
    for (int s = 0; s < 4; s++) {
        bhalf8 a = *reinterpret_cast<const bhalf8*>(&hb[(wv * 16 + m) * 136 + s * 32 + q * 8]);
        #pragma unroll
        for (int t = 0; t < 8; t++) {
            bhalf8 b = *reinterpret_cast<const bhalf8*>(&wlT[(t * 16 + m) * 136 + s * 32 + q * 8]);
            acc2[t] = __builtin_amdgcn_mfma_f32_16x16x32_bf16(a, b, acc2[t], 0, 0, 0);
        }
    }

    // t = leaky(leaky(acc2 + bl)) + h ; layernorm per row ; *0.5
    float tv[8][4];
    float sum[4] = {0, 0, 0, 0}, ssq[4] = {0, 0, 0, 0};
    #pragma unroll
    for (int t = 0; t < 8; t++) {
        float bb = bl[t * 16 + m];
        #pragma unroll
        for (int p = 0; p < 4; p++) {
            int row = wv * 16 + q * 4 + p;
            float h = bf2f((unsigned short)hb[row * 136 + t * 16 + m]);
            float v = leaky(leaky(acc2[t][p] + bb)) + h;
            tv[t][p] = v;
            sum[p] += v; ssq[p] += v * v;
        }
    }
    #pragma unroll
    for (int p = 0; p < 4; p++) {
        #pragma unroll
        for (int d = 1; d < 16; d <<= 1) {   // reduce across the 16 lanes sharing a row-quad
            sum[p] += __shfl_xor(sum[p], d, 64);
            ssq[p] += __shfl_xor(ssq[p], d, 64);
        }
    }
    #pragma unroll
    for (int p = 0; p < 4; p++) {
        float mu  = sum[p] * (1.0f / 128.0f);
        float var = ssq[p] * (1.0f / 128.0f) - mu * mu;
        float rs  = rsqrtf(var + 1e-5f) * 0.5f;
        int row = wv * 16 + q * 4 + p;
        #pragma unroll
        for (int t = 0; t < 8; t++)
            hb[row * 136 + t * 16 + m] = (short)f2bf((tv[t][p] - mu) * rs);
    }
    __syncthreads();
    // coalesced bf16 copy-out (16B chunks)
    for (int c = tid; c < 64 * 16; c += 256) {
        int row = c >> 4, cb = (c & 15) * 8;
        *reinterpret_cast<u32x4*>(&xout[(size_t)(r0 + row) * 128 + cb]) =
            *reinterpret_cast<const u32x4*>(&hb[row * 136 + cb]);
    }
}

// ---------------- prop: gather-mean -> node matmul -> rezero residual ----------------
template <typename TOUT>
__global__ void __launch_bounds__(256)
prop_kernel(const unsigned short* __restrict__ xin, const int* __restrict__ idmap,
            const float* __restrict__ Wn, const float* __restrict__ bn,
            const float* __restrict__ rez, const float* __restrict__ Ww,
            const float* __restrict__ Wv, TOUT* __restrict__ xout,
            float* __restrict__ wout, float* __restrict__ vout, int final_pass)
{
    __shared__ __align__(16) short smem[26112];
    short* wnT  = smem;            // [128][136] Wn^T
    short* fbuf = smem + 17408;    // [64][136]  gathered means (bf16)

    const int tid  = threadIdx.x;
    const int lane = tid & 63;
    const int wv   = tid >> 6;
    const int m    = lane & 15;
    const int q    = lane >> 4;
    const int r0   = blockIdx.x * 64;

    for (int c = tid; c < 128 * 16; c += 256) {
        int n = c & 127, kb = c >> 7;
        bhalf8 t;
        #pragma unroll
        for (int j = 0; j < 8; j++) t[j] = (short)f2bf(Wn[(kb * 8 + j) * 128 + n]);
        *reinterpret_cast<bhalf8*>(&wnT[n * 136 + kb * 8]) = t;
    }
    for (int idx = tid; idx < 64 * 128; idx += 256) {
        int r = idx >> 7, j = idx & 127;
        int gr = r0 + r;
        int i0 = idmap[2 * gr], i1 = idmap[2 * gr + 1];
        float f = 0.5f * (bf2f(xin[(size_t)i0 * 128 + j]) + bf2f(xin[(size_t)i1 * 128 + j]));
        fbuf[r * 136 + j] = (short)f2bf(f);
    }
    __syncthreads();

    // g_pre = f @ Wn  (K=128)
    bhalf8 a[4];
    #pragma unroll
    for (int s = 0; s < 4; s++)
        a[s] = *reinterpret_cast<const bhalf8*>(&fbuf[(wv * 16 + m) * 136 + s * 32 + q * 8]);
    f32x4 acc[8] = {};
    #pragma unroll
    for (int t = 0; t < 8; t++) {
        #pragma unroll
        for (int s = 0; s < 4; s++) {
            bhalf8 b = *reinterpret_cast<const bhalf8*>(&wnT[(t * 16 + m) * 136 + s * 32 + q * 8]);
            acc[t] = __builtin_amdgcn_mfma_f32_16x16x32_bf16(a[s], b, acc[t], 0, 0, 0);
        }
    }

    const float scale = 0.25f * rez[0];   // SCALE_STEPS * rezero
    float xr[8][4];
    float wsum[4] = {0, 0, 0, 0}, vsum[4] = {0, 0, 0, 0};
    #pragma unroll
    for (int t = 0; t < 8; t++) {
        float bb = bn[t * 16 + m];
        float fw = final_pass ? Ww[t * 16 + m] : 0.0f;
        float fv = final_pass ? Wv[t * 16 + m] : 0.0f;
        #pragma unroll
        for (int p = 0; p < 4; p++) {
            int grow = r0 + wv * 16 + q * 4 + p;
            float g  = leaky(acc[t][p] + bb);
            float xo = bf2f(xin[(size_t)grow * 128 + t * 16 + m]);
            float xn = xo + g * scale;
            xr[t][p] = xn;
            wsum[p] += xn * fw; vsum[p] += xn * fv;
        }
    }

    if (final_pass) {
        #pragma unroll
        for (int p = 0; p < 4; p++) {
            #pragma unroll
            for (int d = 1; d < 16; d <<= 1) {
                wsum[p] += __shfl_xor(wsum[p], d, 64);
                vsum[p] += __shfl_xor(vsum[p], d, 64);
            }
        }
        if (m == 0) {
            #pragma unroll
            for (int p = 0; p < 4; p++) {
                int grow = r0 + wv * 16 + q * 4 + p;
                wout[grow] = wsum[p];
                vout[grow] = vsum[p];
            }
        }
    }

    __syncthreads();   // all MFMA LDS reads complete; smem reusable for out-staging

    if (sizeof(TOUT) == 4) {           // fp32 final output via LDS (stride 132 floats)
        float* sout = reinterpret_cast<float*>(smem);
        #pragma unroll
        for (int t = 0; t < 8; t++)
            #pragma unroll
            for (int p = 0; p < 4; p++)
                sout[(wv * 16 + q * 4 + p) * 132 + t * 16 + m] = xr[t][p];
        __syncthreads();
        for (int c = tid; c < 64 * 32; c += 256) {
            int row = c >> 5, cb = (c & 31) * 4;
            *reinterpret_cast<f32x4*>(reinterpret_cast<float*>(xout) + (size_t)(r0 + row) * 128 + cb) =
                *reinterpret_cast<const f32x4*>(&sout[row * 132 + cb]);
        }
    } else {                           // bf16 intermediate via LDS (stride 136 shorts)
        #pragma unroll
        for (int t = 0; t < 8; t++)
            #pragma unroll
            for (int p = 0; p < 4; p++)
                smem[(wv * 16 + q * 4 + p) * 136 + t * 16 + m] = (short)f2bf(xr[t][p]);
        __syncthreads();
        for (int c = tid; c < 64 * 16; c += 256) {
            int row = c >> 4, cb = (c & 15) * 8;
            *reinterpret_cast<u32x4*>(reinterpret_cast<unsigned short*>(xout) + (size_t)(r0 + row) * 128 + cb) =
                *reinterpret_cast<const u32x4*>(&smem[row * 136 + cb]);
        }
    }
}

extern "C" void kernel_launch(void* const* d_in, const int* in_sizes, int n_in,
                              void* d_out, int out_size, void* d_ws, size_t ws_size,
                              hipStream_t stream) {
    const float* feats = (const float*)d_in[0];
    const int*   idmap = (const int*)d_in[2];
    const float* smean = (const float*)d_in[3];
    const float* sstd  = (const float*)d_in[4];
    const float* Wemb  = (const float*)d_in[5];
    const float* bemb  = (const float*)d_in[6];
    const float* Wl    = (const float*)d_in[7];
    const float* bl    = (const float*)d_in[8];
    const float* Wn    = (const float*)d_in[9];
    const float* bn    = (const float*)d_in[10];
    const float* rez   = (const float*)d_in[11];
    const float* Ww    = (const float*)d_in[12];
    const float* Wv    = (const float*)d_in[13];

    float* out = (float*)d_out;
    unsigned short* x0 = (unsigned short*)d_out;   // bf16 scratch in x_main region (dead before final write)
    unsigned short* x1 = (unsigned short*)d_ws;    // bf16 scratch, 64 MB
    float* wout = out + (size_t)NROWS * 128;
    float* vout = wout + NROWS;

    phase_a_kernel<<<NBLK, 256, 0, stream>>>(feats, smean, sstd, Wemb, bemb, Wl, bl, x0);
    prop_kernel<unsigned short><<<NBLK, 256, 0, stream>>>(x0, idmap, Wn, bn, rez, Ww, Wv,
                                                          x1, nullptr, nullptr, 0);
    prop_kernel<float><<<NBLK, 256, 0, stream>>>(x1, idmap, Wn, bn, rez, Ww, Wv,
                                                 out, wout, vout, 1);
}

// Round 4
// 346.097 us; speedup vs baseline: 2.8172x; 1.1860x over previous
//
#include <hip/hip_runtime.h>

// CombineEmbedder R4: fragment-major pre-packed bf16 weights (setup kernel),
// B operands + mm1-A loaded global->VGPR directly, gather->registers,
// residual/heads fused into coalesced copy-out.
// N=262144, FEAT=64, D=128, DEPTH=2.
//
// ws layout (bytes):
//   [0,      16384)  wembF  bf16 frags  (t*2+s)*64+lane, 8 shorts each (norm folded)
//   [16384,  49152)  wlF    bf16 frags  (t*4+s)*64+lane
//   [49152,  81920)  wnF    bf16 frags  (0.5 gather-mean folded)
//   [81920,  82432)  bembP  fp32[128]   (bemb - (mu/sigma) @ Wemb)
//   [1 MB,   65 MB)  x1     bf16 [N][128] ping buffer
// x0 (bf16) aliases d_out's x_main region (dead before final fp32 write).

#define NROWS 262144
#define NBLK  4096

typedef __attribute__((ext_vector_type(8))) short bhalf8;
typedef __attribute__((ext_vector_type(4))) float f32x4;
typedef __attribute__((ext_vector_type(4))) unsigned int u32x4;

__device__ __forceinline__ unsigned short f2bf(float x) {
    union { float f; unsigned u; } v; v.f = x;
    unsigned r = v.u + 0x7FFFu + ((v.u >> 16) & 1u);   // RNE
    return (unsigned short)(r >> 16);
}
__device__ __forceinline__ float bflo(unsigned u) {
    union { unsigned u; float f; } v; v.u = u << 16; return v.f;
}
__device__ __forceinline__ float bfhi(unsigned u) {
    union { unsigned u; float f; } v; v.u = u & 0xFFFF0000u; return v.f;
}
__device__ __forceinline__ float leaky(float x) { return x >= 0.0f ? x : 0.01f * x; }

// ---------------- setup: pack weights to fragment-major bf16, fold norms ----------------
__global__ void __launch_bounds__(256)
setup_kernel(const float* __restrict__ smean, const float* __restrict__ sstd,
             const float* __restrict__ Wemb, const float* __restrict__ bemb,
             const float* __restrict__ Wl, const float* __restrict__ Wn,
             unsigned short* __restrict__ wpack, float* __restrict__ bembP)
{
    int task = blockIdx.x * 256 + threadIdx.x;
    if (blockIdx.x < 160) {
        if (task < 8192) {                       // wembF: frag=(t*2+s), K=64
            int f = task >> 9, idx = task & 511;
            int t = f >> 1, s = f & 1, lane = idx >> 3, j = idx & 7;
            int n = t * 16 + (lane & 15), k = s * 32 + (lane >> 4) * 8 + j;
            wpack[task] = f2bf(Wemb[k * 128 + n] / (sstd[k] + 0.001f));
        } else if (task < 24576) {               // wlF: frag=(t*4+s), K=128
            int u = task - 8192;
            int f = u >> 9, idx = u & 511;
            int t = f >> 2, s = f & 3, lane = idx >> 3, j = idx & 7;
            int n = t * 16 + (lane & 15), k = s * 32 + (lane >> 4) * 8 + j;
            wpack[task] = f2bf(Wl[k * 128 + n]);
        } else if (task < 40960) {               // wnF: 0.5 folded
            int u = task - 24576;
            int f = u >> 9, idx = u & 511;
            int t = f >> 2, s = f & 3, lane = idx >> 3, j = idx & 7;
            int n = t * 16 + (lane & 15), k = s * 32 + (lane >> 4) * 8 + j;
            wpack[task] = f2bf(0.5f * Wn[k * 128 + n]);
        }
    } else {                                     // bembP[n] = bemb[n] - sum_k mu_k/sig_k * Wemb[k][n]
        int n = threadIdx.x;
        if (n < 128) {
            float acc = bemb[n];
            for (int k = 0; k < 64; k++)
                acc -= smean[k] / (sstd[k] + 0.001f) * Wemb[k * 128 + n];
            bembP[n] = acc;
        }
    }
}

// ---------------- phase A: embed + residual layer + layernorm*0.5 ----------------
__global__ void __launch_bounds__(256)
phase_a_kernel(const float* __restrict__ feats,
               const unsigned short* __restrict__ wembF,
               const float* __restrict__ bembP,
               const unsigned short* __restrict__ wlF,
               const float* __restrict__ bl,
               unsigned short* __restrict__ xout)
{
    __shared__ __align__(16) short hb[64 * 136];   // 17408 B
    const int tid = threadIdx.x, lane = tid & 63, wv = tid >> 6;
    const int m = lane & 15, q = lane >> 4;
    const int r0 = blockIdx.x * 64;

    const bhalf8* wbe = (const bhalf8*)wembF;
    const bhalf8* wbl = (const bhalf8*)wlF;

    // mm1 A-fragments straight from feats (norm folded into weights)
    bhalf8 af[2];
    #pragma unroll
    for (int s = 0; s < 2; s++) {
        const float* fp = feats + (size_t)(r0 + wv * 16 + m) * 64 + s * 32 + q * 8;
        f32x4 f0 = *(const f32x4*)fp;
        f32x4 f1 = *(const f32x4*)(fp + 4);
        bhalf8 a;
        #pragma unroll
        for (int jj = 0; jj < 4; jj++) { a[jj] = (short)f2bf(f0[jj]); a[4 + jj] = (short)f2bf(f1[jj]); }
        af[s] = a;
    }
    f32x4 acc[8] = {};
    #pragma unroll
    for (int s = 0; s < 2; s++)
        #pragma unroll
        for (int t = 0; t < 8; t++)
            acc[t] = __builtin_amdgcn_mfma_f32_16x16x32_bf16(af[s], wbe[(t * 2 + s) * 64 + lane], acc[t], 0, 0, 0);

    // h = leaky(acc + bembP): keep fp32 in regs for residual, bf16 to LDS for mm2-A
    float hv[8][4];
    #pragma unroll
    for (int t = 0; t < 8; t++) {
        float be = bembP[t * 16 + m];
        #pragma unroll
        for (int p = 0; p < 4; p++) {
            float h = leaky(acc[t][p] + be);
            hv[t][p] = h;
            hb[(wv * 16 + q * 4 + p) * 136 + t * 16 + m] = (short)f2bf(h);
        }
    }
    // mm2: A from hb (own-tile, in-wave dep only), B from global frags
    f32x4 acc2[8] = {};
    #pragma unroll
    for (int s = 0; s < 4; s++) {
        bhalf8 a = *(const bhalf8*)&hb[(wv * 16 + m) * 136 + s * 32 + q * 8];
        #pragma unroll
        for (int t = 0; t < 8; t++)
            acc2[t] = __builtin_amdgcn_mfma_f32_16x16x32_bf16(a, wbl[(t * 4 + s) * 64 + lane], acc2[t], 0, 0, 0);
    }

    // t = leaky(leaky(acc2+bl)) + h ; layernorm ; *0.5
    float tv[8][4];
    float sum[4] = {0, 0, 0, 0}, ssq[4] = {0, 0, 0, 0};
    #pragma unroll
    for (int t = 0; t < 8; t++) {
        float bb = bl[t * 16 + m];
        #pragma unroll
        for (int p = 0; p < 4; p++) {
            float v = leaky(leaky(acc2[t][p] + bb)) + hv[t][p];
            tv[t][p] = v;
            sum[p] += v; ssq[p] += v * v;
        }
    }
    #pragma unroll
    for (int p = 0; p < 4; p++) {
        #pragma unroll
        for (int d = 1; d < 16; d <<= 1) {
            sum[p] += __shfl_xor(sum[p], d, 64);
            ssq[p] += __shfl_xor(ssq[p], d, 64);
        }
    }
    #pragma unroll
    for (int p = 0; p < 4; p++) {
        float mu  = sum[p] * (1.0f / 128.0f);
        float var = ssq[p] * (1.0f / 128.0f) - mu * mu;
        float rs  = rsqrtf(var + 1e-5f) * 0.5f;
        int row = wv * 16 + q * 4 + p;
        #pragma unroll
        for (int t = 0; t < 8; t++)
            hb[row * 136 + t * 16 + m] = (short)f2bf((tv[t][p] - mu) * rs);   // own-tile overwrite, safe
    }
    __syncthreads();
    for (int c = tid; c < 64 * 16; c += 256) {
        int row = c >> 4, cb = (c & 15) * 8;
        *reinterpret_cast<u32x4*>(&xout[(size_t)(r0 + row) * 128 + cb]) =
            *reinterpret_cast<const u32x4*>(&hb[row * 136 + cb]);
    }
}

// ---------------- prop: gather(+) -> node matmul -> rezero residual (+heads) ----------------
template <typename TOUT>
__global__ void __launch_bounds__(256)
prop_kernel(const unsigned short* __restrict__ xin, const int* __restrict__ idmap,
            const unsigned short* __restrict__ wnF, const float* __restrict__ bn,
            const float* __restrict__ rez, const float* __restrict__ Ww,
            const float* __restrict__ Wv, TOUT* __restrict__ xout,
            float* __restrict__ wout, float* __restrict__ vout, int final_pass)
{
    __shared__ __align__(16) short gls[64 * 136];
    const int tid = threadIdx.x, lane = tid & 63, wv = tid >> 6;
    const int m = lane & 15, q = lane >> 4;
    const int r0 = blockIdx.x * 64;
    const bhalf8* wbn = (const bhalf8*)wnF;

    // gather two rows straight into A-fragments (0.5 folded into Wn)
    const int myrow = r0 + wv * 16 + m;
    int2 ids = ((const int2*)idmap)[myrow];
    const unsigned short* xa = xin + (size_t)ids.x * 128;
    const unsigned short* xb = xin + (size_t)ids.y * 128;
    bhalf8 afr[4];
    #pragma unroll
    for (int s = 0; s < 4; s++) {
        u32x4 ua = *(const u32x4*)(xa + s * 32 + q * 8);
        u32x4 ub = *(const u32x4*)(xb + s * 32 + q * 8);
        bhalf8 o;
        #pragma unroll
        for (int w = 0; w < 4; w++) {
            float lo = bflo(ua[w]) + bflo(ub[w]);
            float hi = bfhi(ua[w]) + bfhi(ub[w]);
            o[2 * w]     = (short)f2bf(lo);
            o[2 * w + 1] = (short)f2bf(hi);
        }
        afr[s] = o;
    }

    f32x4 acc[8] = {};
    #pragma unroll
    for (int s = 0; s < 4; s++)
        #pragma unroll
        for (int t = 0; t < 8; t++)
            acc[t] = __builtin_amdgcn_mfma_f32_16x16x32_bf16(afr[s], wbn[(t * 4 + s) * 64 + lane], acc[t], 0, 0, 0);

    // stage g*scale (bf16) in C-layout
    const float scale = 0.25f * rez[0];
    #pragma unroll
    for (int t = 0; t < 8; t++) {
        float bb = bn[t * 16 + m];
        #pragma unroll
        for (int p = 0; p < 4; p++)
            gls[(wv * 16 + q * 4 + p) * 136 + t * 16 + m] = (short)f2bf(leaky(acc[t][p] + bb) * scale);
    }
    __syncthreads();

    // fused copy-out: xn = x_old + g*scale (coalesced), + heads on final pass
    #pragma unroll
    for (int i = 0; i < 4; i++) {
        int task = i * 256 + tid;
        int row = task >> 4, cb = task & 15;
        u32x4 gv = *(const u32x4*)&gls[row * 136 + cb * 8];
        u32x4 xv = *(const u32x4*)(xin + (size_t)(r0 + row) * 128 + cb * 8);
        float xn[8];
        #pragma unroll
        for (int w = 0; w < 4; w++) {
            xn[2 * w]     = bflo(xv[w]) + bflo(gv[w]);
            xn[2 * w + 1] = bfhi(xv[w]) + bfhi(gv[w]);
        }
        if (!final_pass) {
            u32x4 ov;
            #pragma unroll
            for (int w = 0; w < 4; w++)
                ov[w] = (unsigned)f2bf(xn[2 * w]) | ((unsigned)f2bf(xn[2 * w + 1]) << 16);
            *reinterpret_cast<u32x4*>(reinterpret_cast<unsigned short*>(xout) + (size_t)(r0 + row) * 128 + cb * 8) = ov;
        } else {
            float* op = reinterpret_cast<float*>(xout) + (size_t)(r0 + row) * 128 + cb * 8;
            f32x4 o0, o1;
            #pragma unroll
            for (int w = 0; w < 4; w++) { o0[w] = xn[w]; o1[w] = xn[4 + w]; }
            *reinterpret_cast<f32x4*>(op)     = o0;
            *reinterpret_cast<f32x4*>(op + 4) = o1;
            f32x4 w0 = *(const f32x4*)&Ww[cb * 8], w1 = *(const f32x4*)&Ww[cb * 8 + 4];
            f32x4 v0 = *(const f32x4*)&Wv[cb * 8], v1 = *(const f32x4*)&Wv[cb * 8 + 4];
            float ws = 0.0f, vs = 0.0f;
            #pragma unroll
            for (int w = 0; w < 4; w++) {
                ws += xn[w] * w0[w] + xn[4 + w] * w1[w];
                vs += xn[w] * v0[w] + xn[4 + w] * v1[w];
            }
            #pragma unroll
            for (int d = 1; d < 16; d <<= 1) {
                ws += __shfl_xor(ws, d, 64);
                vs += __shfl_xor(vs, d, 64);
            }
            if ((lane & 15) == 0) { wout[r0 + row] = ws; vout[r0 + row] = vs; }
        }
    }
}

extern "C" void kernel_launch(void* const* d_in, const int* in_sizes, int n_in,
                              void* d_out, int out_size, void* d_ws, size_t ws_size,
                              hipStream_t stream) {
    const float* feats = (const float*)d_in[0];
    const int*   idmap = (const int*)d_in[2];
    const float* smean = (const float*)d_in[3];
    const float* sstd  = (const float*)d_in[4];
    const float* Wemb  = (const float*)d_in[5];
    const float* bemb  = (const float*)d_in[6];
    const float* Wl    = (const float*)d_in[7];
    const float* bl    = (const float*)d_in[8];
    const float* Wn    = (const float*)d_in[9];
    const float* bn    = (const float*)d_in[10];
    const float* rez   = (const float*)d_in[11];
    const float* Ww    = (const float*)d_in[12];
    const float* Wv    = (const float*)d_in[13];

    char* ws = (char*)d_ws;
    unsigned short* wpack = (unsigned short*)ws;          // wembF @0, wlF @8192, wnF @24576 (shorts)
    float*          bembP = (float*)(ws + 81920);
    unsigned short* x1    = (unsigned short*)(ws + (1 << 20));

    float* out = (float*)d_out;
    unsigned short* x0 = (unsigned short*)d_out;          // bf16 scratch in x_main region
    float* wout = out + (size_t)NROWS * 128;
    float* vout = wout + NROWS;

    setup_kernel<<<161, 256, 0, stream>>>(smean, sstd, Wemb, bemb, Wl, Wn, wpack, bembP);
    phase_a_kernel<<<NBLK, 256, 0, stream>>>(feats, wpack, bembP, wpack + 8192, bl, x0);
    prop_kernel<unsigned short><<<NBLK, 256, 0, stream>>>(x0, idmap, wpack + 24576, bn, rez, Ww, Wv,
                                                          x1, nullptr, nullptr, 0);
    prop_kernel<float><<<NBLK, 256, 0, stream>>>(x1, idmap, wpack + 24576, bn, rez, Ww, Wv,
                                                 out, wout, vout, 1);
}